// Round 6
// baseline (296.787 us; speedup 1.0000x reference)
//
#include <hip/hip_runtime.h>
#include <hip/hip_cooperative_groups.h>

namespace cg = cooperative_groups;

#define NB 32
#define NF 64
#define NN 128
#define EPSF 1e-9f

typedef float f32x4 __attribute__((ext_vector_type(4)));

// round-to-nearest-even f32 -> bf16 (as low 16 bits of return)
__device__ __forceinline__ unsigned bf16rne(float f) {
  unsigned u = __float_as_uint(f);
  return (u + 0x7FFFu + ((u >> 16) & 1u)) >> 16;
}

// ===========================================================================
// FUSED cooperative kernel: 512 blocks x 256 threads, 2 blocks/CU
// (LDS-forced: 64.6 KB). Block g owns 4 matrices: b = g>>4, f = (g&15)*4+m.
// Phase A: float4 read -> swizzled f32 LDS tile for stats + bf16 reg copy.
// __threadfence (release) -> grid.sync -> __threadfence (acquire).
// Finalize: wave m reduces 32 batch partials of its f (now coherent).
// Phase B: out from bf16 registers; x is read from HBM exactly ONCE.
// Total HBM traffic 268 MB vs 402 MB for the two-pass version.
// ===========================================================================
__global__ __launch_bounds__(256, 2) void mfb_fused(
    const float* __restrict__ x, const float* __restrict__ mask,
    const float* __restrict__ w, const float* __restrict__ wexp,
    const float* __restrict__ wbias, const float* __restrict__ bias,
    const float* __restrict__ rmean, const float* __restrict__ rvar,
    const int* __restrict__ steps, float* __restrict__ mean_bf,
    float* __restrict__ var_bf, f32x4* __restrict__ out4) {
  __shared__ float tile[NN * NN];  // 64 KB
  __shared__ float smask[NN];
  __shared__ float red[12];
  __shared__ float sc[12];  // per matrix: rm, s, bias

  const int tid = threadIdx.x;
  const int g = blockIdx.x;
  const int b = g >> 4;
  const int fbase = (g & 15) << 2;
  const int lane = tid & 63;

  float m0 = mask[b * NN + lane];
  float m1 = mask[b * NN + 64 + lane];
  float msq0 = m0 * m0, msq1 = m1 * m1;
  if (tid < NN) smask[tid] = mask[b * NN + tid];

  unsigned xrA[32], xrB[32], xrC[32], xrD[32];

#define PHASE_A(XR, MIDX)                                                    \
  {                                                                          \
    const int bf = b * NF + fbase + MIDX;                                    \
    const f32x4* xp4 = (const f32x4*)(x + (size_t)bf * (NN * NN));           \
    _Pragma("unroll")                                                        \
    for (int c = 0; c < 16; ++c) {                                           \
      f32x4 v = xp4[c * 256 + tid];                                          \
      int i = 8 * c + (tid >> 5);                                            \
      int ci = i & 31;                                                       \
      int k0 = (tid & 31) << 2;                                              \
      tile[i * NN + ((k0    ) ^ ci)] = v.x;                                  \
      tile[i * NN + ((k0 + 1) ^ ci)] = v.y;                                  \
      tile[i * NN + ((k0 + 2) ^ ci)] = v.z;                                  \
      tile[i * NN + ((k0 + 3) ^ ci)] = v.w;                                  \
      XR[2 * c]     = bf16rne(v.x) | (bf16rne(v.y) << 16);                   \
      XR[2 * c + 1] = bf16rne(v.z) | (bf16rne(v.w) << 16);                   \
    }                                                                        \
    __syncthreads();                                                         \
    float tr = 0.f, nump = 0.f;                                              \
    if (tid < 64) nump = msq0 + msq1;                                        \
    if (tid < 128) {                                                         \
      float d = tile[tid * NN + (tid ^ (tid & 31))];                         \
      tr = d * ((tid < 64) ? msq0 : msq1);                                   \
    }                                                                        \
    const int irow = tid >> 1;                                               \
    const int k00 = (tid & 1) << 6;                                          \
    float mq = (irow < 64) ? __shfl(msq0, irow, 64)                          \
                           : __shfl(msq1, irow - 64, 64);                    \
    const int cxor = irow & 31;                                              \
    const int rowbase = irow * NN;                                           \
    float acc = 0.f;                                                         \
    _Pragma("unroll")                                                        \
    for (int c = 0; c < 64; ++c) {                                           \
      int k = k00 + c;                                                       \
      float a = tile[rowbase + (k ^ cxor)];                                  \
      float bt = tile[k * NN + (irow ^ (k & 31))];                           \
      acc = fmaf(a, bt, acc);                                                \
    }                                                                        \
    float trsq = acc * mq;                                                   \
    _Pragma("unroll")                                                        \
    for (int off = 32; off > 0; off >>= 1) {                                 \
      tr   += __shfl_down(tr, off, 64);                                      \
      trsq += __shfl_down(trsq, off, 64);                                    \
      nump += __shfl_down(nump, off, 64);                                    \
    }                                                                        \
    __syncthreads();                                                         \
    if (lane == 0) {                                                         \
      int wv = tid >> 6;                                                     \
      red[wv * 3 + 0] = tr;                                                  \
      red[wv * 3 + 1] = trsq;                                                \
      red[wv * 3 + 2] = nump;                                                \
    }                                                                        \
    __syncthreads();                                                         \
    if (tid == 0) {                                                          \
      float trs = red[0] + red[3] + red[6] + red[9];                         \
      float tq  = red[1] + red[4] + red[7] + red[10];                        \
      float num = red[2] + red[5] + red[8] + red[11];                        \
      float num2 = fmaxf(num - 1.f, 1.f);                                    \
      mean_bf[bf] = trs / num;                                               \
      var_bf[bf]  = tq / num2 - trs * trs / (num * num2);                    \
    }                                                                        \
  }

  PHASE_A(xrA, 0)
  PHASE_A(xrB, 1)
  PHASE_A(xrC, 2)
  PHASE_A(xrD, 3)
#undef PHASE_A

  // release: force this block's partial stores out of the XCD-local L2
  __threadfence();
  cg::this_grid().sync();
  // acquire: invalidate stale cached lines before reading other XCDs' partials
  __threadfence();

  // finalize: wave m handles matrix m (lanes 0-31 reduce over the 32 batches)
  {
    int m = tid >> 6;
    int ln = tid & 63;
    int f = fbase + m;
    if (ln < 32) {
      float ms = mean_bf[ln * NF + f];
      float vs = var_bf[ln * NF + f];
#pragma unroll
      for (int off = 16; off > 0; off >>= 1) {
        ms += __shfl_down(ms, off, 32);
        vs += __shfl_down(vs, off, 32);
      }
      if (ln == 0) {
        ms *= (1.f / NB);
        vs *= (1.f / NB);
        int st = steps[0];
        float mom = 0.997f;
        if (st < 100) {
          float beta = (float)st * 0.01f;
          mom = 0.997f * beta + 0.8f * (1.f - beta);
        }
        float rmv = mom * rmean[f] + (1.f - mom) * ms;
        float rvv = mom * rvar[f] + (1.f - mom) * vs;
        float gain = w[f] * expf(wexp[f]) + wbias[f];
        sc[m * 3 + 0] = rmv;
        sc[m * 3 + 1] = gain / (sqrtf(rvv) + EPSF);
        sc[m * 3 + 2] = bias[f];
      }
    }
    __syncthreads();
  }

  const f32x4 mj4 = ((const f32x4*)smask)[tid & 31];

#define PHASE_B(XR, MIDX)                                                    \
  {                                                                          \
    const int bf = b * NF + fbase + MIDX;                                    \
    const float rm = sc[MIDX * 3 + 0];                                       \
    const float ss = sc[MIDX * 3 + 1];                                       \
    const float bi = sc[MIDX * 3 + 2];                                       \
    f32x4* op = out4 + (size_t)bf * 4096;                                    \
    _Pragma("unroll")                                                        \
    for (int c = 0; c < 16; ++c) {                                           \
      int i = 8 * c + (tid >> 5);                                            \
      int k0 = (tid & 31) << 2;                                              \
      unsigned p0 = XR[2 * c], p1 = XR[2 * c + 1];                           \
      float x0 = __uint_as_float(p0 << 16);                                  \
      float x1 = __uint_as_float(p0 & 0xFFFF0000u);                          \
      float x2 = __uint_as_float(p1 << 16);                                  \
      float x3 = __uint_as_float(p1 & 0xFFFF0000u);                          \
      float cs = smask[i] * ss;                                              \
      f32x4 o;                                                               \
      o.x = (x0 - ((i == k0    ) ? rm : 0.f)) * (cs * mj4.x) + ((i == k0    ) ? bi : 0.f); \
      o.y = (x1 - ((i == k0 + 1) ? rm : 0.f)) * (cs * mj4.y) + ((i == k0 + 1) ? bi : 0.f); \
      o.z = (x2 - ((i == k0 + 2) ? rm : 0.f)) * (cs * mj4.z) + ((i == k0 + 2) ? bi : 0.f); \
      o.w = (x3 - ((i == k0 + 3) ? rm : 0.f)) * (cs * mj4.w) + ((i == k0 + 3) ? bi : 0.f); \
      __builtin_nontemporal_store(o, &op[c * 256 + tid]);                    \
    }                                                                        \
  }

  PHASE_B(xrA, 0)
  PHASE_B(xrB, 1)
  PHASE_B(xrC, 2)
  PHASE_B(xrD, 3)
#undef PHASE_B
}

// ===========================================================================
// FALLBACK path (verbatim round-5 passing kernels), used only if the
// cooperative launch is rejected (e.g. unsupported under graph capture).
// ===========================================================================
__global__ __launch_bounds__(256) void mfb_stats(
    const float* __restrict__ x, const float* __restrict__ mask,
    float* __restrict__ mean_bf, float* __restrict__ var_bf) {
  __shared__ float tile[NN * NN];
  const int tid = threadIdx.x;
  const int bf = blockIdx.x;
  const int b = bf >> 6;
  const float* xp = x + (size_t)bf * (NN * NN);
  const int lane = tid & 63;

  float m0 = mask[b * NN + lane];
  float m1 = mask[b * NN + 64 + lane];
  float msq0 = m0 * m0;
  float msq1 = m1 * m1;

  const int kcol = tid & 127;
  const int ib = tid >> 7;
#pragma unroll 8
  for (int c = 0; c < 64; ++c) {
    int i = 2 * c + ib;
    tile[i * NN + (kcol ^ (i & 31))] = xp[c * 256 + tid];
  }
  __syncthreads();

  float tr = 0.f, nump = 0.f;
  if (tid < 64) nump = msq0 + msq1;
  if (tid < 128) {
    float d = tile[tid * NN + (tid ^ (tid & 31))];
    tr = d * ((tid < 64) ? msq0 : msq1);
  }

  const int irow = tid >> 1;
  const int k0 = (tid & 1) << 6;
  float mq = (irow < 64) ? __shfl(msq0, irow, 64) : __shfl(msq1, irow - 64, 64);
  const int cxor = irow & 31;
  const int rowbase = irow * NN;
  float acc = 0.f;
#pragma unroll
  for (int c = 0; c < 64; ++c) {
    int k = k0 + c;
    float a = tile[rowbase + (k ^ cxor)];
    float bt = tile[k * NN + (irow ^ (k & 31))];
    acc = fmaf(a, bt, acc);
  }
  float trsq = acc * mq;

#pragma unroll
  for (int off = 32; off > 0; off >>= 1) {
    tr   += __shfl_down(tr, off, 64);
    trsq += __shfl_down(trsq, off, 64);
    nump += __shfl_down(nump, off, 64);
  }
  __syncthreads();
  if (lane == 0) {
    int w = tid >> 6;
    tile[w * 3 + 0] = tr;
    tile[w * 3 + 1] = trsq;
    tile[w * 3 + 2] = nump;
  }
  __syncthreads();
  if (tid == 0) {
    float trs = tile[0] + tile[3] + tile[6] + tile[9];
    float tq  = tile[1] + tile[4] + tile[7] + tile[10];
    float num = tile[2] + tile[5] + tile[8] + tile[11];
    float num2 = fmaxf(num - 1.f, 1.f);
    mean_bf[bf] = trs / num;
    var_bf[bf]  = tq / num2 - trs * trs / (num * num2);
  }
}

__global__ __launch_bounds__(256) void mfb_apply(
    const f32x4* __restrict__ x4, const float* __restrict__ mask,
    const float* __restrict__ mean_bf, const float* __restrict__ var_bf,
    const float* __restrict__ w, const float* __restrict__ wexp,
    const float* __restrict__ wbias, const float* __restrict__ bias,
    const float* __restrict__ rmean, const float* __restrict__ rvar,
    const int* __restrict__ steps, f32x4* __restrict__ out4) {
  const int bf = blockIdx.x;
  const int b = bf >> 6;
  const int f = bf & 63;
  const int tid = threadIdx.x;
  __shared__ float smask[NN];
  __shared__ float sc[3];

  if (tid < NN) smask[tid] = mask[b * NN + tid];
  if (tid < 32) {
    float ms = mean_bf[tid * NF + f];
    float vs = var_bf[tid * NF + f];
#pragma unroll
    for (int off = 16; off > 0; off >>= 1) {
      ms += __shfl_down(ms, off, 32);
      vs += __shfl_down(vs, off, 32);
    }
    if (tid == 0) {
      ms *= (1.f / NB);
      vs *= (1.f / NB);
      int st = steps[0];
      float mom = 0.997f;
      if (st < 100) {
        float beta = (float)st * 0.01f;
        mom = 0.997f * beta + 0.8f * (1.f - beta);
      }
      float rm = mom * rmean[f] + (1.f - mom) * ms;
      float rv = mom * rvar[f] + (1.f - mom) * vs;
      float gain = w[f] * expf(wexp[f]) + wbias[f];
      sc[0] = rm;
      sc[1] = gain / (sqrtf(rv) + EPSF);
      sc[2] = bias[f];
    }
  }
  __syncthreads();

  const float rm = sc[0];
  const float s = sc[1];
  const float bi = sc[2];
  const f32x4 mj4 = ((const f32x4*)smask)[tid & 31];
  const int j0 = (tid & 31) << 2;
  const int wv = tid >> 5;
  const f32x4* xp = x4 + (size_t)bf * 4096;
  f32x4* op = out4 + (size_t)bf * 4096;

#pragma unroll
  for (int c = 0; c < 16; ++c) {
    const int idx = c * 256 + tid;
    const int i = c * 8 + wv;
    f32x4 xv = xp[idx];
    float cs = smask[i] * s;
    f32x4 o;
    o.x = (xv.x - ((i == j0    ) ? rm : 0.f)) * (cs * mj4.x) + ((i == j0    ) ? bi : 0.f);
    o.y = (xv.y - ((i == j0 + 1) ? rm : 0.f)) * (cs * mj4.y) + ((i == j0 + 1) ? bi : 0.f);
    o.z = (xv.z - ((i == j0 + 2) ? rm : 0.f)) * (cs * mj4.z) + ((i == j0 + 2) ? bi : 0.f);
    o.w = (xv.w - ((i == j0 + 3) ? rm : 0.f)) * (cs * mj4.w) + ((i == j0 + 3) ? bi : 0.f);
    __builtin_nontemporal_store(o, &op[idx]);
  }
}

extern "C" void kernel_launch(void* const* d_in, const int* in_sizes, int n_in,
                              void* d_out, int out_size, void* d_ws, size_t ws_size,
                              hipStream_t stream) {
  const float* x     = (const float*)d_in[0];
  const float* mask  = (const float*)d_in[1];
  const float* w     = (const float*)d_in[2];
  const float* wexp  = (const float*)d_in[3];
  const float* wbias = (const float*)d_in[4];
  const float* bias  = (const float*)d_in[5];
  const float* rmean = (const float*)d_in[6];
  const float* rvar  = (const float*)d_in[7];
  const int*   steps = (const int*)d_in[8];

  float* ws = (float*)d_ws;
  float* mean_bf = ws;            // [B*F]
  float* var_bf  = ws + NB * NF;  // [B*F]
  f32x4* out     = (f32x4*)d_out;

  void* kargs[] = {(void*)&x,     (void*)&mask,  (void*)&w,
                   (void*)&wexp,  (void*)&wbias, (void*)&bias,
                   (void*)&rmean, (void*)&rvar,  (void*)&steps,
                   (void*)&mean_bf, (void*)&var_bf, (void*)&out};
  hipError_t err = hipLaunchCooperativeKernel((void*)mfb_fused, dim3(512),
                                              dim3(256), kargs, 0, stream);
  if (err != hipSuccess) {
    // cooperative launch unavailable (e.g. under graph capture): two-pass path
    mfb_stats<<<NB * NF, 256, 0, stream>>>(x, mask, mean_bf, var_bf);
    mfb_apply<<<NB * NF, 256, 0, stream>>>((const f32x4*)x, mask, mean_bf,
                                           var_bf, w, wexp, wbias, bias, rmean,
                                           rvar, steps, (f32x4*)d_out);
  }
}

// Round 8
// 70.200 us; speedup vs baseline: 4.2278x; 4.2278x over previous
//
#include <hip/hip_runtime.h>
#include <hip/hip_fp16.h>

#define NB 32
#define NF 64
#define NN 128
#define EPSF 1e-9f

typedef float f32x4 __attribute__((ext_vector_type(4)));
typedef unsigned short u16x4 __attribute__((ext_vector_type(4)));

__device__ __forceinline__ unsigned short f2h(float f) {
  __half h = __float2half_rn(f);
  return *reinterpret_cast<unsigned short*>(&h);
}
__device__ __forceinline__ float h2f(unsigned short u) {
  __half h = *reinterpret_cast<__half*>(&u);
  return __half2float(h);
}

// ---------------------------------------------------------------------------
// Pass 1: per-(b,f) masked trace / trace-of-square / node count (exact f32).
// If WRITE_H != 0, also writes an fp16 copy of the matrix to d_ws (67 MB;
// phase-A unique footprint 134+67=201 MB < 256 MB Infinity Cache, so pass 2's
// re-read of the copy should be an L3 hit).
// Staging: scalar coalesced loads -> swizzled LDS writes (proven 0-conflict:
// addr = i*128 + (k ^ (i&31))); the fp16 store is contiguous ushort (dense).
// ---------------------------------------------------------------------------
template <int WRITE_H>
__global__ __launch_bounds__(256) void mfb_stats(
    const float* __restrict__ x, const float* __restrict__ mask,
    float* __restrict__ mean_bf, float* __restrict__ var_bf,
    unsigned short* __restrict__ hws) {
  __shared__ float tile[NN * NN];  // 64 KB, reused for block reduction
  const int tid = threadIdx.x;
  const int bf = blockIdx.x;
  const int b = bf >> 6;
  const float* xp = x + (size_t)bf * (NN * NN);
  unsigned short* hp = hws + (size_t)bf * (NN * NN);
  const int lane = tid & 63;

  float m0 = mask[b * NN + lane];
  float m1 = mask[b * NN + 64 + lane];
  float msq0 = m0 * m0;
  float msq1 = m1 * m1;

  const int kcol = tid & 127;
  const int ib = tid >> 7;  // 0 or 1
#pragma unroll 8
  for (int c = 0; c < 64; ++c) {
    int i = 2 * c + ib;
    float v = xp[c * 256 + tid];
    tile[i * NN + (kcol ^ (i & 31))] = v;
    if (WRITE_H) hp[c * 256 + tid] = f2h(v);
  }
  __syncthreads();

  float tr = 0.f, nump = 0.f;
  if (tid < 64) nump = msq0 + msq1;  // count num once (wave 0 only)
  if (tid < 128) {
    // diagonal element x[i,i], i = tid
    float d = tile[tid * NN + (tid ^ (tid & 31))];
    tr = d * ((tid < 64) ? msq0 : msq1);
  }

  // trace of x@x: each thread owns half of row irow (64 columns)
  const int irow = tid >> 1;
  const int k0 = (tid & 1) << 6;
  float mq = (irow < 64) ? __shfl(msq0, irow, 64) : __shfl(msq1, irow - 64, 64);
  const int cxor = irow & 31;
  const int rowbase = irow * NN;
  float acc = 0.f;
#pragma unroll
  for (int c = 0; c < 64; ++c) {
    int k = k0 + c;
    float a = tile[rowbase + (k ^ cxor)];          // x[irow, k]
    float bt = tile[k * NN + (irow ^ (k & 31))];   // x[k, irow]
    acc = fmaf(a, bt, acc);
  }
  float trsq = acc * mq;

  // block reduction: wave shfl, then LDS (reusing tile) across 4 waves
#pragma unroll
  for (int off = 32; off > 0; off >>= 1) {
    tr   += __shfl_down(tr, off, 64);
    trsq += __shfl_down(trsq, off, 64);
    nump += __shfl_down(nump, off, 64);
  }
  __syncthreads();  // all tile reads complete before reuse
  if (lane == 0) {
    int w = tid >> 6;
    tile[w * 3 + 0] = tr;
    tile[w * 3 + 1] = trsq;
    tile[w * 3 + 2] = nump;
  }
  __syncthreads();
  if (tid == 0) {
    float trs = tile[0] + tile[3] + tile[6] + tile[9];
    float tq  = tile[1] + tile[4] + tile[7] + tile[10];
    float num = tile[2] + tile[5] + tile[8] + tile[11];
    float num2 = fmaxf(num - 1.f, 1.f);
    mean_bf[bf] = trs / num;
    var_bf[bf]  = tq / num2 - trs * trs / (num * num2);
  }
}

// ---------------------------------------------------------------------------
// Pass 2: finalize (in-block batch reduction of partials) + apply.
// SRC_H=1: read the fp16 copy from d_ws (L3-resident) via u16x4 (8 B/lane).
// SRC_H=0: read f32 x via f32x4 (fallback, round-5 behavior).
// f32x4 NON-TEMPORAL stores (out never re-read; avoid evicting the ws copy).
// ---------------------------------------------------------------------------
template <int SRC_H>
__global__ __launch_bounds__(256) void mfb_apply(
    const unsigned short* __restrict__ hws, const f32x4* __restrict__ x4,
    const float* __restrict__ mask, const float* __restrict__ mean_bf,
    const float* __restrict__ var_bf, const float* __restrict__ w,
    const float* __restrict__ wexp, const float* __restrict__ wbias,
    const float* __restrict__ bias, const float* __restrict__ rmean,
    const float* __restrict__ rvar, const int* __restrict__ steps,
    f32x4* __restrict__ out4) {
  const int bf = blockIdx.x;
  const int b = bf >> 6;
  const int f = bf & 63;
  const int tid = threadIdx.x;
  __shared__ float smask[NN];
  __shared__ float sc[3];  // rm, s, bias[f]

  if (tid < NN) smask[tid] = mask[b * NN + tid];
  if (tid < 32) {
    float ms = mean_bf[tid * NF + f];
    float vs = var_bf[tid * NF + f];
#pragma unroll
    for (int off = 16; off > 0; off >>= 1) {
      ms += __shfl_down(ms, off, 32);
      vs += __shfl_down(vs, off, 32);
    }
    if (tid == 0) {
      ms *= (1.f / NB);
      vs *= (1.f / NB);
      int st = steps[0];
      float mom = 0.997f;
      if (st < 100) {
        float beta = (float)st * 0.01f;
        mom = 0.997f * beta + 0.8f * (1.f - beta);
      }
      float rm = mom * rmean[f] + (1.f - mom) * ms;
      float rv = mom * rvar[f] + (1.f - mom) * vs;
      float gain = w[f] * expf(wexp[f]) + wbias[f];
      sc[0] = rm;
      sc[1] = gain / (sqrtf(rv) + EPSF);
      sc[2] = bias[f];
    }
  }
  __syncthreads();

  const float rm = sc[0];
  const float s = sc[1];
  const float bi = sc[2];
  const f32x4 mj4 = ((const f32x4*)smask)[tid & 31];
  const int j0 = (tid & 31) << 2;
  const int wv = tid >> 5;
  const u16x4* hp = (const u16x4*)hws + (size_t)bf * 4096;
  const f32x4* xp = x4 + (size_t)bf * 4096;
  f32x4* op = out4 + (size_t)bf * 4096;

#pragma unroll
  for (int c = 0; c < 16; ++c) {
    const int idx = c * 256 + tid;
    const int i = c * 8 + wv;
    float x0, x1, x2, x3;
    if (SRC_H) {
      u16x4 hv = hp[idx];
      x0 = h2f(hv.x); x1 = h2f(hv.y); x2 = h2f(hv.z); x3 = h2f(hv.w);
    } else {
      f32x4 xv = xp[idx];
      x0 = xv.x; x1 = xv.y; x2 = xv.z; x3 = xv.w;
    }
    float cs = smask[i] * s;
    f32x4 o;
    o.x = (x0 - ((i == j0    ) ? rm : 0.f)) * (cs * mj4.x) + ((i == j0    ) ? bi : 0.f);
    o.y = (x1 - ((i == j0 + 1) ? rm : 0.f)) * (cs * mj4.y) + ((i == j0 + 1) ? bi : 0.f);
    o.z = (x2 - ((i == j0 + 2) ? rm : 0.f)) * (cs * mj4.z) + ((i == j0 + 2) ? bi : 0.f);
    o.w = (x3 - ((i == j0 + 3) ? rm : 0.f)) * (cs * mj4.w) + ((i == j0 + 3) ? bi : 0.f);
    __builtin_nontemporal_store(o, &op[idx]);
  }
}

extern "C" void kernel_launch(void* const* d_in, const int* in_sizes, int n_in,
                              void* d_out, int out_size, void* d_ws, size_t ws_size,
                              hipStream_t stream) {
  const float* x     = (const float*)d_in[0];
  const float* mask  = (const float*)d_in[1];
  const float* w     = (const float*)d_in[2];
  const float* wexp  = (const float*)d_in[3];
  const float* wbias = (const float*)d_in[4];
  const float* bias  = (const float*)d_in[5];
  const float* rmean = (const float*)d_in[6];
  const float* rvar  = (const float*)d_in[7];
  const int*   steps = (const int*)d_in[8];

  float* ws = (float*)d_ws;
  float* mean_bf = ws;                        // [B*F] f32
  float* var_bf  = ws + NB * NF;              // [B*F] f32
  unsigned short* hws = (unsigned short*)(ws + 2 * NB * NF);  // fp16 x copy

  const size_t need = (size_t)2 * NB * NF * 4 +
                      (size_t)NB * NF * NN * NN * 2;  // 16 KB + 67 MB

  if (ws_size >= need) {
    mfb_stats<1><<<NB * NF, 256, 0, stream>>>(x, mask, mean_bf, var_bf, hws);
    mfb_apply<1><<<NB * NF, 256, 0, stream>>>(hws, (const f32x4*)x, mask,
                                              mean_bf, var_bf, w, wexp, wbias,
                                              bias, rmean, rvar, steps,
                                              (f32x4*)d_out);
  } else {
    // ws too small for the fp16 copy: validated round-5 two-pass path
    mfb_stats<0><<<NB * NF, 256, 0, stream>>>(x, mask, mean_bf, var_bf, hws);
    mfb_apply<0><<<NB * NF, 256, 0, stream>>>(hws, (const f32x4*)x, mask,
                                              mean_bf, var_bf, w, wexp, wbias,
                                              bias, rmean, rvar, steps,
                                              (f32x4*)d_out);
  }
}